// Round 8
// baseline (93.291 us; speedup 1.0000x reference)
//
#include <hip/hip_runtime.h>
#include <hip/hip_bf16.h>

#define D_NODE 16
#define D_EDGE 8
#define D_IN   40
#define D_HID  64
#define NG     500
#define TPB    256
#define WARPS  (TPB / 64)

typedef __attribute__((ext_vector_type(8))) short bf16x8;
typedef __attribute__((ext_vector_type(4))) short bf16x4;
typedef __attribute__((ext_vector_type(4))) float f32x4;

__device__ __forceinline__ short f2bf(float f) {
    union { __hip_bfloat16 h; short s; } u;
    u.h = __float2bfloat16(f);   // RNE (setup-only; per-tile paths use cvt_pk)
    return u.s;
}

// HW packed bf16 convert (RNE): D[15:0]=bf16(lo), D[31:16]=bf16(hi).
__device__ __forceinline__ int cvt_pk(float lo, float hi) {
    int r;
    asm("v_cvt_pk_bf16_f32 %0, %1, %2" : "=v"(r) : "v"(lo), "v"(hi));
    return r;
}

#if __has_builtin(__builtin_amdgcn_mfma_f32_16x16x16bf16_1k)
#define MFMA16(A, B, C) __builtin_amdgcn_mfma_f32_16x16x16bf16_1k(A, B, C, 0, 0, 0)
#else
static __device__ __forceinline__ f32x4 mfma16_asm(bf16x4 a, bf16x4 b, f32x4 c) {
    asm volatile("v_mfma_f32_16x16x16_bf16 %0, %1, %2, %0"
                 : "+v"(c) : "v"(a), "v"(b));
    return c;
}
#define MFMA16(A, B, C) mfma16_asm(A, B, C)
#endif

// Round-6 verified structure (4-tile groups, 3-stage pipeline, swizzled LDS
// staging). Exactly two changes:
//   (1) per-tile bf16 converts via v_cvt_pk_bf16_f32 (HW RNE, bit-identical)
//   (2) W2 fragments + b1/b2/W3 in block-shared LDS (-80 VGPRs -> occupancy)
__global__ __launch_bounds__(TPB) void mof_mfma6(
    const float* __restrict__ x, const float* __restrict__ ea,
    const float* __restrict__ W1, const float* __restrict__ b1,
    const float* __restrict__ W2, const float* __restrict__ b2,
    const float* __restrict__ W3, const float* __restrict__ b3,
    const int* __restrict__ ei, const int* __restrict__ batch,
    float* __restrict__ out, int E)
{
    __shared__ __align__(16) char  mbuf[WARPS][4][16 * 128];  // 32 KB
    __shared__ __align__(8)  short a2frag[4][4][64][4];       // 8 KB W2 frags
    __shared__ __align__(16) float sh_b1[D_HID];
    __shared__ __align__(16) float sh_b2[D_HID];
    __shared__ __align__(16) float sh_w3[D_HID];
    __shared__ float gacc[NG];

    // zero mbuf (pad cols 40..63 must stay 0); init weight tables + gacc
    for (int i = threadIdx.x; i < (int)sizeof(mbuf) / 4; i += TPB)
        reinterpret_cast<int*>(mbuf)[i] = 0;
    for (int i = threadIdx.x; i < D_HID; i += TPB) {
        sh_b1[i] = b1[i];
        sh_b2[i] = b2[i];
        sh_w3[i] = W3[i];
    }
    for (int i = threadIdx.x; i < 4 * 4 * 64; i += TPB) {
        const int kb = i >> 8, nb = (i >> 6) & 3, ln = i & 63;
        const int qq = ln >> 4, rr = ln & 15;
        #pragma unroll
        for (int j = 0; j < 4; ++j)
            a2frag[kb][nb][ln][j] = f2bf(W2[(kb * 16 + qq * 4 + j) * D_HID + nb * 16 + rr]);
    }
    for (int g = threadIdx.x; g < NG; g += TPB) gacc[g] = 0.f;
    __syncthreads();

    const int lane = threadIdx.x & 63;
    const int q    = lane >> 4;    // quarter-wave 0..3
    const int r15  = lane & 15;
    const int er   = lane >> 2;    // staging: edge-in-tile
    const int p    = lane & 3;     // staging: 4-float part
    const int sw_w = (er & 7) << 4;
    const int sw_r = (r15 & 7) << 4;
    char* const mb0 = mbuf[threadIdx.x >> 6][0];
    char* const mb1 = mbuf[threadIdx.x >> 6][1];
    char* const mb2 = mbuf[threadIdx.x >> 6][2];
    char* const mb3 = mbuf[threadIdx.x >> 6][3];

    // ---- per-lane W1 fragments in registers (verbatim round 6) ----
    bf16x8 w1f[2][4];
    #pragma unroll
    for (int kb = 0; kb < 2; ++kb)
        #pragma unroll
        for (int nb = 0; nb < 4; ++nb)
            #pragma unroll
            for (int j = 0; j < 8; ++j) {
                const int k = kb * 32 + q * 8 + j;
                const int n = nb * 16 + r15;
                w1f[kb][nb][j] = (k < D_IN) ? f2bf(W1[k * D_HID + n]) : (short)0;
            }
    const float b3v = b3[0];

    const int ntiles  = (E + 15) >> 4;
    const int ngroups = (ntiles + 3) >> 2;
    const int wid = (blockIdx.x * TPB + threadIdx.x) >> 6;
    const int nw  = (gridDim.x * TPB) >> 6;

    auto ld_idx = [&](int t, int& s4, int& d4) {
        int tb = t < ntiles ? t : ntiles - 1;
        int e4 = (tb << 4) + er; if (e4 >= E) e4 = E - 1;
        s4 = ei[e4];
        d4 = ei[E + e4];
    };
    auto ld_x = [&](int t, int s4, int d4, float4& xd, float4& xs, float4& ev) {
        int tb = t < ntiles ? t : ntiles - 1;
        int e4 = (tb << 4) + er; if (e4 >= E) e4 = E - 1;
        xd = *reinterpret_cast<const float4*>(x + (size_t)d4 * D_NODE + p * 4);
        xs = *reinterpret_cast<const float4*>(x + (size_t)s4 * D_NODE + p * 4);
        if (p < 2) ev = *reinterpret_cast<const float4*>(ea + (size_t)e4 * D_EDGE + p * 4);
    };
    // cvt_pk + swizzled LDS write (addresses verbatim round 6)
    auto write_tile = [&](char* mb, const float4& xd, const float4& xs, const float4& ev) {
        int2 v;
        v.x = cvt_pk(xd.x, xd.y); v.y = cvt_pk(xd.z, xd.w);
        *reinterpret_cast<int2*>(mb + er * 128 + ((p * 8) ^ sw_w)) = v;
        v.x = cvt_pk(xs.x, xs.y); v.y = cvt_pk(xs.z, xs.w);
        *reinterpret_cast<int2*>(mb + er * 128 + ((32 + p * 8) ^ sw_w)) = v;
        if (p < 2) {
            v.x = cvt_pk(ev.x, ev.y); v.y = cvt_pk(ev.z, ev.w);
            *reinterpret_cast<int2*>(mb + er * 128 + ((64 + p * 8) ^ sw_w)) = v;
        }
    };
    // MFMA chain + reduce + scatter (structure verbatim round 6; W2/biases from LDS)
    auto compute_tile = [&](const char* mb, int tbase) {
        const bf16x8 bm0 = *reinterpret_cast<const bf16x8*>(mb + r15 * 128 + ((q * 16) ^ sw_r));
        const bf16x8 bm1 = *reinterpret_cast<const bf16x8*>(mb + r15 * 128 + ((64 + q * 16) ^ sw_r));
        f32x4 acc1[4];
        #pragma unroll
        for (int nb = 0; nb < 4; ++nb)
            acc1[nb] = *reinterpret_cast<const f32x4*>(&sh_b1[nb * 16 + q * 4]);
        #pragma unroll
        for (int nb = 0; nb < 4; ++nb) {
            acc1[nb] = __builtin_amdgcn_mfma_f32_16x16x32_bf16(w1f[0][nb], bm0, acc1[nb], 0, 0, 0);
            acc1[nb] = __builtin_amdgcn_mfma_f32_16x16x32_bf16(w1f[1][nb], bm1, acc1[nb], 0, 0, 0);
        }
        f32x4 acc2[4];
        #pragma unroll
        for (int nb = 0; nb < 4; ++nb)
            acc2[nb] = *reinterpret_cast<const f32x4*>(&sh_b2[nb * 16 + q * 4]);
        #pragma unroll
        for (int kb = 0; kb < 4; ++kb) {
            union { int2 i2; bf16x4 v; } hu;
            hu.i2.x = cvt_pk(fmaxf(acc1[kb][0], 0.f), fmaxf(acc1[kb][1], 0.f));
            hu.i2.y = cvt_pk(fmaxf(acc1[kb][2], 0.f), fmaxf(acc1[kb][3], 0.f));
            const bf16x4 hb = hu.v;
            #pragma unroll
            for (int nb = 0; nb < 4; ++nb) {
                const bf16x4 a2 = *reinterpret_cast<const bf16x4*>(a2frag[kb][nb][lane]);
                acc2[nb] = MFMA16(a2, hb, acc2[nb]);
            }
        }
        float msg = 0.f;
        #pragma unroll
        for (int nb = 0; nb < 4; ++nb) {
            const f32x4 w3 = *reinterpret_cast<const f32x4*>(&sh_w3[nb * 16 + q * 4]);
            #pragma unroll
            for (int rr = 0; rr < 4; ++rr)
                msg = fmaf(fmaxf(acc2[nb][rr], 0.f), w3[rr], msg);
        }
        msg += __shfl_xor(msg, 16);
        msg += __shfl_xor(msg, 32);
        const int e = tbase + r15;
        if (q == 0 && e < E) {
            const int d = ei[E + e];
            atomicAdd(&gacc[batch[d]], msg + b3v);
        }
    };

    if (wid < ngroups) {
        int G = wid;
        int is0, id0, is1, id1, is2, id2, is3, id3;
        float4 xdA, xsA, evA = make_float4(0.f, 0.f, 0.f, 0.f);
        float4 xdB, xsB, evB = make_float4(0.f, 0.f, 0.f, 0.f);

        ld_idx(4 * G + 0, is0, id0); ld_idx(4 * G + 1, is1, id1);
        ld_idx(4 * G + 2, is2, id2); ld_idx(4 * G + 3, is3, id3);
        ld_x(4 * G + 0, is0, id0, xdA, xsA, evA);
        ld_x(4 * G + 1, is1, id1, xdB, xsB, evB);
        write_tile(mb0, xdA, xsA, evA);
        write_tile(mb1, xdB, xsB, evB);
        ld_x(4 * G + 2, is2, id2, xdA, xsA, evA);
        ld_x(4 * G + 3, is3, id3, xdB, xsB, evB);
        write_tile(mb2, xdA, xsA, evA);
        write_tile(mb3, xdB, xsB, evB);
        {
            const int Gn = G + nw;
            ld_idx(4 * Gn + 0, is0, id0); ld_idx(4 * Gn + 1, is1, id1);
            ld_idx(4 * Gn + 2, is2, id2); ld_idx(4 * Gn + 3, is3, id3);
        }

        for (;;) {
            const int Gn = G + nw;
            const int t0 = 4 * G;
            if (Gn < ngroups) {
                ld_x(4 * Gn + 0, is0, id0, xdA, xsA, evA);
                ld_x(4 * Gn + 1, is1, id1, xdB, xsB, evB);
                asm volatile("s_waitcnt lgkmcnt(0)" ::: "memory");
                compute_tile(mb0, (t0 + 0) << 4);
                compute_tile(mb1, (t0 + 1) << 4);
                write_tile(mb0, xdA, xsA, evA);
                write_tile(mb1, xdB, xsB, evB);
                ld_x(4 * Gn + 2, is2, id2, xdA, xsA, evA);
                ld_x(4 * Gn + 3, is3, id3, xdB, xsB, evB);
                const int Gnn = Gn + nw;
                ld_idx(4 * Gnn + 0, is0, id0); ld_idx(4 * Gnn + 1, is1, id1);
                ld_idx(4 * Gnn + 2, is2, id2); ld_idx(4 * Gnn + 3, is3, id3);
                asm volatile("s_waitcnt lgkmcnt(0)" ::: "memory");
                compute_tile(mb2, (t0 + 2) << 4);
                compute_tile(mb3, (t0 + 3) << 4);
                write_tile(mb2, xdA, xsA, evA);
                write_tile(mb3, xdB, xsB, evB);
                G = Gn;
            } else {
                asm volatile("s_waitcnt lgkmcnt(0)" ::: "memory");
                compute_tile(mb0, (t0 + 0) << 4);
                compute_tile(mb1, (t0 + 1) << 4);
                compute_tile(mb2, (t0 + 2) << 4);
                compute_tile(mb3, (t0 + 3) << 4);
                break;
            }
        }
    }

    __syncthreads();
    for (int g = threadIdx.x; g < NG; g += TPB) {
        const float v = gacc[g];
        if (v != 0.f) atomicAdd(&out[g], 0.5f * v);
    }
}

extern "C" void kernel_launch(void* const* d_in, const int* in_sizes, int n_in,
                              void* d_out, int out_size, void* d_ws, size_t ws_size,
                              hipStream_t stream) {
    const float* x  = (const float*)d_in[0];
    const float* ea = (const float*)d_in[1];
    const float* W1 = (const float*)d_in[2];
    const float* b1 = (const float*)d_in[3];
    const float* W2 = (const float*)d_in[4];
    const float* b2 = (const float*)d_in[5];
    const float* W3 = (const float*)d_in[6];
    const float* b3 = (const float*)d_in[7];
    const int*   ei    = (const int*)d_in[8];
    const int*   batch = (const int*)d_in[9];
    float* out = (float*)d_out;

    const int E = in_sizes[1] / D_EDGE;

    hipMemsetAsync(d_out, 0, (size_t)out_size * sizeof(float), stream);

    const int blocks = 1024;   // 4096 waves, ~6 groups (24 tiles) per wave
    mof_mfma6<<<blocks, TPB, 0, stream>>>(x, ea, W1, b1, W2, b2, W3, b3,
                                          ei, batch, out, E);
}

// Round 10
// 82.276 us; speedup vs baseline: 1.1339x; 1.1339x over previous
//
#include <hip/hip_runtime.h>
#include <hip/hip_bf16.h>

#define D_NODE 16
#define D_EDGE 8
#define D_IN   40
#define D_HID  64
#define NG     500
#define TPB    256
#define WARPS  (TPB / 64)

typedef __attribute__((ext_vector_type(8))) short bf16x8;
typedef __attribute__((ext_vector_type(4))) short bf16x4;
typedef __attribute__((ext_vector_type(4))) float f32x4;

__device__ __forceinline__ short f2bf(float f) {
    union { __hip_bfloat16 h; short s; } u;
    u.h = __float2bfloat16(f);   // RNE (setup-only; per-tile paths use cvt_pk)
    return u.s;
}

// HW packed bf16 convert (RNE): D[15:0]=bf16(lo), D[31:16]=bf16(hi).
__device__ __forceinline__ int cvt_pk(float lo, float hi) {
    int r;
    asm("v_cvt_pk_bf16_f32 %0, %1, %2" : "=v"(r) : "v"(lo), "v"(hi));
    return r;
}

#if __has_builtin(__builtin_amdgcn_mfma_f32_16x16x16bf16_1k)
#define MFMA16(A, B, C) __builtin_amdgcn_mfma_f32_16x16x16bf16_1k(A, B, C, 0, 0, 0)
#else
static __device__ __forceinline__ f32x4 mfma16_asm(bf16x4 a, bf16x4 b, f32x4 c) {
    asm volatile("v_mfma_f32_16x16x16_bf16 %0, %1, %2, %0"
                 : "+v"(c) : "v"(a), "v"(b));
    return c;
}
#define MFMA16(A, B, C) mfma16_asm(A, B, C)
#endif

// Round-8 verified base (cvt_pk + a2frag-in-LDS, 4-tile groups, 3-stage
// pipeline). ONE change (bisecting round 9's NaN): scatter-g prefetched one
// group ahead via g = batch[shfl(id, 4*r15)] using the already-staged edge
// indices -> removes the chained ei->batch gather tail from compute_tile.
// W1 fragments stay in registers (round 9's a1frag change reverted).
__global__ __launch_bounds__(TPB) void mof_mfma8(
    const float* __restrict__ x, const float* __restrict__ ea,
    const float* __restrict__ W1, const float* __restrict__ b1,
    const float* __restrict__ W2, const float* __restrict__ b2,
    const float* __restrict__ W3, const float* __restrict__ b3,
    const int* __restrict__ ei, const int* __restrict__ batch,
    float* __restrict__ out, int E)
{
    __shared__ __align__(16) char  mbuf[WARPS][4][16 * 128];  // 32 KB
    __shared__ __align__(8)  short a2frag[4][4][64][4];       // 8 KB W2 frags
    __shared__ __align__(16) float sh_b1[D_HID];
    __shared__ __align__(16) float sh_b2[D_HID];
    __shared__ __align__(16) float sh_w3[D_HID];
    __shared__ float gacc[NG];

    // zero mbuf (pad cols 40..63 must stay 0); init weight tables + gacc
    for (int i = threadIdx.x; i < (int)sizeof(mbuf) / 4; i += TPB)
        reinterpret_cast<int*>(mbuf)[i] = 0;
    for (int i = threadIdx.x; i < D_HID; i += TPB) {
        sh_b1[i] = b1[i];
        sh_b2[i] = b2[i];
        sh_w3[i] = W3[i];
    }
    for (int i = threadIdx.x; i < 4 * 4 * 64; i += TPB) {
        const int kb = i >> 8, nb = (i >> 6) & 3, ln = i & 63;
        const int qq = ln >> 4, rr = ln & 15;
        #pragma unroll
        for (int j = 0; j < 4; ++j)
            a2frag[kb][nb][ln][j] = f2bf(W2[(kb * 16 + qq * 4 + j) * D_HID + nb * 16 + rr]);
    }
    for (int g = threadIdx.x; g < NG; g += TPB) gacc[g] = 0.f;
    __syncthreads();

    const int lane = threadIdx.x & 63;
    const int q    = lane >> 4;    // quarter-wave 0..3
    const int r15  = lane & 15;
    const int er   = lane >> 2;    // staging: edge-in-tile
    const int p    = lane & 3;     // staging: 4-float part
    const int sw_w = (er & 7) << 4;
    const int sw_r = (r15 & 7) << 4;
    char* const mb0 = mbuf[threadIdx.x >> 6][0];
    char* const mb1 = mbuf[threadIdx.x >> 6][1];
    char* const mb2 = mbuf[threadIdx.x >> 6][2];
    char* const mb3 = mbuf[threadIdx.x >> 6][3];

    // ---- per-lane W1 fragments in registers (verbatim round 8) ----
    bf16x8 w1f[2][4];
    #pragma unroll
    for (int kb = 0; kb < 2; ++kb)
        #pragma unroll
        for (int nb = 0; nb < 4; ++nb)
            #pragma unroll
            for (int j = 0; j < 8; ++j) {
                const int k = kb * 32 + q * 8 + j;
                const int n = nb * 16 + r15;
                w1f[kb][nb][j] = (k < D_IN) ? f2bf(W1[k * D_HID + n]) : (short)0;
            }
    const float b3v = b3[0];

    const int ntiles  = (E + 15) >> 4;
    const int ngroups = (ntiles + 3) >> 2;
    const int wid = (blockIdx.x * TPB + threadIdx.x) >> 6;
    const int nw  = (gridDim.x * TPB) >> 6;

    auto ld_idx = [&](int t, int& s4, int& d4) {
        int tb = t < ntiles ? t : ntiles - 1;
        int e4 = (tb << 4) + er; if (e4 >= E) e4 = E - 1;
        s4 = ei[e4];
        d4 = ei[E + e4];
    };
    auto ld_x = [&](int t, int s4, int d4, float4& xd, float4& xs, float4& ev) {
        int tb = t < ntiles ? t : ntiles - 1;
        int e4 = (tb << 4) + er; if (e4 >= E) e4 = E - 1;
        xd = *reinterpret_cast<const float4*>(x + (size_t)d4 * D_NODE + p * 4);
        xs = *reinterpret_cast<const float4*>(x + (size_t)s4 * D_NODE + p * 4);
        if (p < 2) ev = *reinterpret_cast<const float4*>(ea + (size_t)e4 * D_EDGE + p * 4);
    };
    // graph id for the edge this lane will scatter (used by q==0 lanes):
    // staging lane 4*r15 holds dst of edge tbase+r15.
    auto ld_g = [&](int d4) -> int {
        return batch[__shfl(d4, r15 << 2)];
    };
    // cvt_pk + swizzled LDS write (verbatim round 8)
    auto write_tile = [&](char* mb, const float4& xd, const float4& xs, const float4& ev) {
        int2 v;
        v.x = cvt_pk(xd.x, xd.y); v.y = cvt_pk(xd.z, xd.w);
        *reinterpret_cast<int2*>(mb + er * 128 + ((p * 8) ^ sw_w)) = v;
        v.x = cvt_pk(xs.x, xs.y); v.y = cvt_pk(xs.z, xs.w);
        *reinterpret_cast<int2*>(mb + er * 128 + ((32 + p * 8) ^ sw_w)) = v;
        if (p < 2) {
            v.x = cvt_pk(ev.x, ev.y); v.y = cvt_pk(ev.z, ev.w);
            *reinterpret_cast<int2*>(mb + er * 128 + ((64 + p * 8) ^ sw_w)) = v;
        }
    };
    // MFMA chain + reduce + scatter (verbatim round 8 except prefetched g)
    auto compute_tile = [&](const char* mb, int tbase, int g) {
        const bf16x8 bm0 = *reinterpret_cast<const bf16x8*>(mb + r15 * 128 + ((q * 16) ^ sw_r));
        const bf16x8 bm1 = *reinterpret_cast<const bf16x8*>(mb + r15 * 128 + ((64 + q * 16) ^ sw_r));
        f32x4 acc1[4];
        #pragma unroll
        for (int nb = 0; nb < 4; ++nb)
            acc1[nb] = *reinterpret_cast<const f32x4*>(&sh_b1[nb * 16 + q * 4]);
        #pragma unroll
        for (int nb = 0; nb < 4; ++nb) {
            acc1[nb] = __builtin_amdgcn_mfma_f32_16x16x32_bf16(w1f[0][nb], bm0, acc1[nb], 0, 0, 0);
            acc1[nb] = __builtin_amdgcn_mfma_f32_16x16x32_bf16(w1f[1][nb], bm1, acc1[nb], 0, 0, 0);
        }
        f32x4 acc2[4];
        #pragma unroll
        for (int nb = 0; nb < 4; ++nb)
            acc2[nb] = *reinterpret_cast<const f32x4*>(&sh_b2[nb * 16 + q * 4]);
        #pragma unroll
        for (int kb = 0; kb < 4; ++kb) {
            union { int2 i2; bf16x4 v; } hu;
            hu.i2.x = cvt_pk(fmaxf(acc1[kb][0], 0.f), fmaxf(acc1[kb][1], 0.f));
            hu.i2.y = cvt_pk(fmaxf(acc1[kb][2], 0.f), fmaxf(acc1[kb][3], 0.f));
            const bf16x4 hb = hu.v;
            #pragma unroll
            for (int nb = 0; nb < 4; ++nb) {
                const bf16x4 a2 = *reinterpret_cast<const bf16x4*>(a2frag[kb][nb][lane]);
                acc2[nb] = MFMA16(a2, hb, acc2[nb]);
            }
        }
        float msg = 0.f;
        #pragma unroll
        for (int nb = 0; nb < 4; ++nb) {
            const f32x4 w3 = *reinterpret_cast<const f32x4*>(&sh_w3[nb * 16 + q * 4]);
            #pragma unroll
            for (int rr = 0; rr < 4; ++rr)
                msg = fmaf(fmaxf(acc2[nb][rr], 0.f), w3[rr], msg);
        }
        msg += __shfl_xor(msg, 16);
        msg += __shfl_xor(msg, 32);
        const int e = tbase + r15;
        if (q == 0 && e < E) atomicAdd(&gacc[g], msg + b3v);
    };

    if (wid < ngroups) {
        int G = wid;
        int is0, id0, is1, id1, is2, id2, is3, id3;
        int g0c, g1c, g2c, g3c, g0n, g1n, g2n, g3n;
        float4 xdA, xsA, evA = make_float4(0.f, 0.f, 0.f, 0.f);
        float4 xdB, xsB, evB = make_float4(0.f, 0.f, 0.f, 0.f);

        ld_idx(4 * G + 0, is0, id0); ld_idx(4 * G + 1, is1, id1);
        ld_idx(4 * G + 2, is2, id2); ld_idx(4 * G + 3, is3, id3);
        ld_x(4 * G + 0, is0, id0, xdA, xsA, evA);
        ld_x(4 * G + 1, is1, id1, xdB, xsB, evB);
        write_tile(mb0, xdA, xsA, evA);
        write_tile(mb1, xdB, xsB, evB);
        ld_x(4 * G + 2, is2, id2, xdA, xsA, evA);
        ld_x(4 * G + 3, is3, id3, xdB, xsB, evB);
        write_tile(mb2, xdA, xsA, evA);
        write_tile(mb3, xdB, xsB, evB);
        // scatter-g for group G (id regs still hold G's indices)
        g0c = ld_g(id0); g1c = ld_g(id1); g2c = ld_g(id2); g3c = ld_g(id3);
        {
            const int Gn = G + nw;
            ld_idx(4 * Gn + 0, is0, id0); ld_idx(4 * Gn + 1, is1, id1);
            ld_idx(4 * Gn + 2, is2, id2); ld_idx(4 * Gn + 3, is3, id3);
        }

        for (;;) {
            const int Gn = G + nw;
            const int t0 = 4 * G;
            if (Gn < ngroups) {
                ld_x(4 * Gn + 0, is0, id0, xdA, xsA, evA);
                ld_x(4 * Gn + 1, is1, id1, xdB, xsB, evB);
                asm volatile("s_waitcnt lgkmcnt(0)" ::: "memory");
                compute_tile(mb0, (t0 + 0) << 4, g0c);
                compute_tile(mb1, (t0 + 1) << 4, g1c);
                g0n = ld_g(id0); g1n = ld_g(id1);     // group Gn, ~full-phase cover
                write_tile(mb0, xdA, xsA, evA);
                write_tile(mb1, xdB, xsB, evB);
                ld_x(4 * Gn + 2, is2, id2, xdA, xsA, evA);
                ld_x(4 * Gn + 3, is3, id3, xdB, xsB, evB);
                g2n = ld_g(id2); g3n = ld_g(id3);     // before id overwrite below
                const int Gnn = Gn + nw;
                ld_idx(4 * Gnn + 0, is0, id0); ld_idx(4 * Gnn + 1, is1, id1);
                ld_idx(4 * Gnn + 2, is2, id2); ld_idx(4 * Gnn + 3, is3, id3);
                asm volatile("s_waitcnt lgkmcnt(0)" ::: "memory");
                compute_tile(mb2, (t0 + 2) << 4, g2c);
                compute_tile(mb3, (t0 + 3) << 4, g3c);
                write_tile(mb2, xdA, xsA, evA);
                write_tile(mb3, xdB, xsB, evB);
                g0c = g0n; g1c = g1n; g2c = g2n; g3c = g3n;
                G = Gn;
            } else {
                asm volatile("s_waitcnt lgkmcnt(0)" ::: "memory");
                compute_tile(mb0, (t0 + 0) << 4, g0c);
                compute_tile(mb1, (t0 + 1) << 4, g1c);
                compute_tile(mb2, (t0 + 2) << 4, g2c);
                compute_tile(mb3, (t0 + 3) << 4, g3c);
                break;
            }
        }
    }

    __syncthreads();
    for (int g = threadIdx.x; g < NG; g += TPB) {
        const float v = gacc[g];
        if (v != 0.f) atomicAdd(&out[g], 0.5f * v);
    }
}

extern "C" void kernel_launch(void* const* d_in, const int* in_sizes, int n_in,
                              void* d_out, int out_size, void* d_ws, size_t ws_size,
                              hipStream_t stream) {
    const float* x  = (const float*)d_in[0];
    const float* ea = (const float*)d_in[1];
    const float* W1 = (const float*)d_in[2];
    const float* b1 = (const float*)d_in[3];
    const float* W2 = (const float*)d_in[4];
    const float* b2 = (const float*)d_in[5];
    const float* W3 = (const float*)d_in[6];
    const float* b3 = (const float*)d_in[7];
    const int*   ei    = (const int*)d_in[8];
    const int*   batch = (const int*)d_in[9];
    float* out = (float*)d_out;

    const int E = in_sizes[1] / D_EDGE;

    hipMemsetAsync(d_out, 0, (size_t)out_size * sizeof(float), stream);

    const int blocks = 1024;   // 4096 waves (verbatim round 8)
    mof_mfma8<<<blocks, TPB, 0, stream>>>(x, ea, W1, b1, W2, b2, W3, b3,
                                          ei, batch, out, E);
}